// Round 9
// baseline (257.445 us; speedup 1.0000x reference)
//
#include <hip/hip_runtime.h>
#include <hip/hip_bf16.h>

typedef __hip_bfloat16 bf16;
using f32x4v = __attribute__((ext_vector_type(4))) float;
using bf16x8 = __attribute__((ext_vector_type(8))) short;

#define N_NODES 25000
#define N_PAD   25024   // multiple of 32 for conv kernel tiles
#define N_EDGES 400000
#define N_GR    100
#define SCAN_C  25      // 1024 * 25 = 25600 >= N_NODES

__device__ __forceinline__ bf16 tob(float v) { return __float2bfloat16(v); }
__device__ __forceinline__ unsigned short tobu(float v) {
  union { bf16 b; unsigned short u; } c; c.b = __float2bfloat16(v); return c.u;
}
__device__ __forceinline__ float b2f(unsigned short u) { return __uint_as_float(((unsigned)u) << 16); }
// clamp-free tanh: 1 - 2/(e^{2x}+1); inf-safe
__device__ __forceinline__ float tanh_fast(float x) {
  float e = __expf(2.f * x);
  return 1.f - 2.f * __builtin_amdgcn_rcpf(e + 1.f);
}

// ---------------- CSR build ----------------
__global__ __launch_bounds__(256) void hist_kernel(const int* __restrict__ dst, int* __restrict__ deg, int E) {
  int e = blockIdx.x * blockDim.x + threadIdx.x;
  if (e < E) atomicAdd(&deg[dst[e]], 1);
}

// one-pass scan: thread-local 25-chunk scan in registers + block scan of totals
__global__ __launch_bounds__(1024) void scan_kernel(const int* __restrict__ deg, int* __restrict__ offs,
                                                    int* __restrict__ cur, int n) {
  __shared__ int wsum[16];
  __shared__ int wpre[16];
  int t = threadIdx.x, lane = t & 63, w = t >> 6;
  int base = t * SCAN_C;
  int loc[SCAN_C];
  int s = 0;
  #pragma unroll
  for (int i = 0; i < SCAN_C; i++) {
    int idx = base + i;
    int v = (idx < n) ? deg[idx] : 0;
    loc[i] = s; s += v;
  }
  int x = s;
  #pragma unroll
  for (int sh = 1; sh < 64; sh <<= 1) { int y = __shfl_up(x, sh); if (lane >= sh) x += y; }
  if (lane == 63) wsum[w] = x;
  __syncthreads();
  if (w == 0 && lane < 16) {
    int ws_ = wsum[lane], xs = ws_;
    #pragma unroll
    for (int sh = 1; sh < 16; sh <<= 1) { int y = __shfl_up(xs, sh); if (lane >= sh) xs += y; }
    wpre[lane] = xs - ws_;
  }
  __syncthreads();
  int excl = wpre[w] + x - s;
  #pragma unroll
  for (int i = 0; i < SCAN_C; i++) {
    int idx = base + i;
    if (idx < n) { int o = excl + loc[i]; offs[idx] = o; cur[idx] = o; }
  }
  if (t == 1023) offs[n] = excl + s;
}

// ---------------- weight prep (+ zero deg + graph bounds) ----------------
// wE per layer (1352 f32): for j in 0..21: 60-float block
//   [w1row(j) 12][w2row(j) 12][w3row(j) 12][wl(j) 12][wg(j) 12]   (11 real + 1 pad each)
// then [attv 32]
__global__ __launch_bounds__(256) void prep_kernel(const float* __restrict__ e1, const float* __restrict__ e2,
                                                   const float* __restrict__ e3, const float* __restrict__ e4,
                                                   const float* __restrict__ attv, const float* __restrict__ convw,
                                                   const float* __restrict__ outw,
                                                   const int* __restrict__ batch,
                                                   float* __restrict__ wE, bf16* __restrict__ Wt,
                                                   bf16* __restrict__ owB, int* __restrict__ gb,
                                                   int* __restrict__ deg) {
  int i = blockIdx.x * blockDim.x + threadIdx.x;
  if (i < N_NODES) deg[i] = 0;
  if (i < 2 * 1352) {
    int l = i / 1352, r = i % 1352;
    float v = 0.f;
    if (r < 1320) {
      int j = r / 60, q = r % 60;
      int blk = q / 12, kk = q % 12;
      if (kk < 11) {
        if (blk == 0)      v = e1[l*242 + kk*22 + j];
        else if (blk == 1) v = e2[l*242 + kk*22 + j];
        else if (blk == 2) v = e3[l*242 + kk*22 + j];
        else if (blk == 3) v = e4[l*484 + j*11 + kk];
        else               v = e4[l*484 + (22 + j)*11 + kk];
      }
    } else {
      v = attv[l*32 + (r - 1320)];
    }
    wE[i] = v;
  }
  int t = i - 2 * 1352;
  if (t >= 0 && t < 2 * 32 * 352) {
    int l = t / (32 * 352), q = t % (32 * 352);
    int o = q / 352, dk = q % 352;
    int d = dk / 11, kk = dk % 11;
    float v = 0.f;
    if (o < 30) v = convw[l*10560 + (kk*32 + d)*30 + o];
    Wt[t] = tob(v);
  }
  int u = i - 2 * 1352 - 2 * 32 * 352;
  if (u >= 0 && u < 2048) {
    int l = u >> 10, rem = u & 1023;
    int hf = rem >> 9, rem2 = rem & 511;
    int lane = rem2 >> 3, j = rem2 & 7;
    int k = (lane >> 4) * 8 + j, n = lane & 15;
    owB[u] = tob(outw[l*1024 + k*32 + hf*16 + n]);
  }
  int g = i - 2 * 1352 - 2 * 32 * 352 - 2048;
  if (g >= 0 && g <= N_GR) {
    if (g == N_GR) { gb[g] = N_NODES; }
    else {
      int lo = 0, hi = N_NODES;
      while (lo < hi) { int mid = (lo + hi) >> 1; if (batch[mid] < g) lo = mid + 1; else hi = mid; }
      gb[g] = lo;
    }
  }
}

// ---------------- fused embedding + h_proj(layer 0) ----------------
__global__ __launch_bounds__(256) void emb_hproj_kernel(const float* __restrict__ x, const float* __restrict__ w,
                                                        const float* __restrict__ b, const float* __restrict__ w1,
                                                        float* __restrict__ h, float* __restrict__ hp,
                                                        unsigned short* __restrict__ hpb, int N) {
  __shared__ float semb[16 * 32];
  __shared__ float sw1[32 * 32];
  __shared__ float sb[32];
  __shared__ float sx[8][16];
  __shared__ float sh[8][33];
  int tid = threadIdx.x;
  for (int i = tid; i < 16 * 32; i += 256) semb[i] = w[i];
  for (int i = tid; i < 32 * 32; i += 256) sw1[i] = w1[i];
  if (tid < 32) sb[tid] = b[tid];
  int nb = blockIdx.x * 8;
  if (tid < 128) {
    int n = nb + (tid >> 4), k = tid & 15;
    sx[tid >> 4][k] = (n < N) ? x[(size_t)n * 16 + k] : 0.f;
  }
  __syncthreads();
  int grp = tid >> 5, d = tid & 31;
  int n = nb + grp;
  float acc = sb[d];
  #pragma unroll
  for (int k = 0; k < 16; k++) acc += sx[grp][k] * semb[k*32 + d];
  sh[grp][d] = acc;
  if (n < N) h[(size_t)n * 32 + d] = acc;
  __syncthreads();
  float hpv = 0.f;
  #pragma unroll
  for (int k = 0; k < 32; k++) hpv += sh[grp][k] * sw1[k*32 + d];
  if (n < N) {
    hp[(size_t)n * 32 + d] = hpv;
    hpb[(size_t)n * 32 + d] = tobu(hpv);
  }
}

// ---------------- edge MLP + raw attention -> CSR payload ----------------
// weights in LDS; ping-pong register double-buffer over j removes per-iteration load stalls
#define EDGE_STEP(B) { \
  const float* w_ = (const float*)(B); \
  float l1 = 0.f, l2 = 0.f, l3 = 0.f; \
  _Pragma("unroll") \
  for (int k = 0; k < 11; k++) l1 += a[k] * w_[k]; \
  _Pragma("unroll") \
  for (int k = 0; k < 11; k++) l2 += a[k] * w_[12 + k]; \
  _Pragma("unroll") \
  for (int k = 0; k < 11; k++) l3 += a[k] * w_[24 + k]; \
  float gg = tanh_fast(l2) * tanh_fast(l3); \
  l1 = fmaxf(l1, 0.f); \
  _Pragma("unroll") \
  for (int k = 0; k < 11; k++) acc[k] += l1 * w_[36 + k] + gg * w_[48 + k]; \
}

__global__ __launch_bounds__(256) void edge_kernel(const float* __restrict__ eattr,
                                                   const int* __restrict__ srcA,
                                                   const int* __restrict__ dstA,
                                                   int* __restrict__ cur,
                                                   int* __restrict__ elist,
                                                   int* __restrict__ epos,
                                                   const unsigned short* __restrict__ hpb,
                                                   const float* __restrict__ wEl,
                                                   uint4* __restrict__ pay, int first, int E) {
  __shared__ float swE[1352];
  for (int i = threadIdx.x; i < 1352; i += 256) swE[i] = wEl[i];
  __syncthreads();
  const float4* w4 = (const float4*)swE;
  int e = blockIdx.x * blockDim.x + threadIdx.x;
  bool live = e < E;
  float a[11], acc[11];
  #pragma unroll
  for (int k = 0; k < 11; k++) {
    a[k] = live ? eattr[(size_t)e*11 + k] : 0.f;
    acc[k] = 0.f;
  }
  // CSR slot assignment overlapped with the MLP compute
  int pp = 0;
  if (live) {
    if (first) {
      pp = atomicAdd(&cur[dstA[e]], 1);
      elist[pp] = e;
      epos[e] = pp;
    } else {
      pp = epos[e];
    }
  }
  float4 b0[15], b1[15];
  #pragma unroll
  for (int i = 0; i < 15; i++) b0[i] = w4[i];
  for (int j = 0; j < 22; j += 2) {
    #pragma unroll
    for (int i = 0; i < 15; i++) b1[i] = w4[(j + 1) * 15 + i];
    EDGE_STEP(b0);
    if (j + 2 < 22) {
      #pragma unroll
      for (int i = 0; i < 15; i++) b0[i] = w4[(j + 2) * 15 + i];
    }
    EDGE_STEP(b1);
  }
  if (!live) return;
  const float* av = swE + 1320;
  float mean = 0.f;
  #pragma unroll
  for (int k = 0; k < 11; k++) { acc[k] = fmaxf(acc[k], 0.f); mean += acc[k]; }
  mean *= (1.f / 11.f);
  int s = srcA[e];
  const uint2* hb = (const uint2*)(hpb + (size_t)s * 32);
  float dot = 0.f;
  #pragma unroll
  for (int q = 0; q < 8; q++) {
    uint2 hv = hb[q];
    dot += b2f((unsigned short)hv.x) * av[q*4+0] + b2f((unsigned short)(hv.x >> 16)) * av[q*4+1]
         + b2f((unsigned short)hv.y) * av[q*4+2] + b2f((unsigned short)(hv.y >> 16)) * av[q*4+3];
  }
  float raw = mean * dot;
  unsigned p[6];
  #pragma unroll
  for (int q = 0; q < 5; q++)
    p[q] = (unsigned)tobu(acc[2*q]) | ((unsigned)tobu(acc[2*q+1]) << 16);
  p[5] = (unsigned)tobu(acc[10]);
  pay[(size_t)pp * 2]     = make_uint4(p[0], p[1], p[2], p[3]);
  pay[(size_t)pp * 2 + 1] = make_uint4(p[4], p[5], __float_as_uint(raw), (unsigned)s);
}

// ---------------- per-node aggregation: softmax scan then branch-free reduction ----------------
__device__ __forceinline__ void unpack_pay(uint4 p0, uint4 p1, float* ev) {
  ev[0] = b2f((unsigned short)p0.x); ev[1] = b2f((unsigned short)(p0.x >> 16));
  ev[2] = b2f((unsigned short)p0.y); ev[3] = b2f((unsigned short)(p0.y >> 16));
  ev[4] = b2f((unsigned short)p0.z); ev[5] = b2f((unsigned short)(p0.z >> 16));
  ev[6] = b2f((unsigned short)p0.w); ev[7] = b2f((unsigned short)(p0.w >> 16));
  ev[8] = b2f((unsigned short)p1.x); ev[9] = b2f((unsigned short)(p1.x >> 16));
  ev[10] = b2f((unsigned short)p1.y);
}

__global__ __launch_bounds__(256) void node_kernel(const int* __restrict__ offs, const int* __restrict__ elist,
                                                   const uint4* __restrict__ pay,
                                                   const unsigned short* __restrict__ hpb,
                                                   bf16* __restrict__ Abuf, float* __restrict__ atts, int N) {
  int wid = threadIdx.x >> 6, lane = threadIdx.x & 63;
  int half = lane >> 5, d = lane & 31;
  int n = blockIdx.x * 4 + wid;
  if (n >= N_PAD) return;
  int beg = 0, deg = 0;
  if (n < N) { beg = offs[n]; deg = offs[n + 1] - beg; }
  const float* payf = (const float*)pay;

  float M, inv;
  float einv_reg = 0.f;
  bool fast = (deg <= 64);
  if (fast) {
    float r = (lane < deg) ? payf[(size_t)(beg + lane) * 8 + 6] : -1e30f;
    float mm = r;
    #pragma unroll
    for (int sh = 1; sh < 64; sh <<= 1) mm = fmaxf(mm, __shfl_xor(mm, sh));
    M = mm;
    float ex = (lane < deg) ? __expf(r - M) : 0.f;
    float ss = ex;
    #pragma unroll
    for (int sh = 1; sh < 64; sh <<= 1) ss += __shfl_xor(ss, sh);
    inv = 1.f / (ss + 1e-16f);
    einv_reg = ex * inv;
    if (lane < deg) atts[elist[beg + lane]] = einv_reg;
  } else {
    float m_l = -1e30f;
    for (int jj = lane; jj < deg; jj += 64)
      m_l = fmaxf(m_l, payf[(size_t)(beg + jj) * 8 + 6]);
    #pragma unroll
    for (int sh = 1; sh < 64; sh <<= 1) m_l = fmaxf(m_l, __shfl_xor(m_l, sh));
    M = m_l;
    float s_l = 0.f;
    for (int jj = lane; jj < deg; jj += 64)
      s_l += __expf(payf[(size_t)(beg + jj) * 8 + 6] - M);
    #pragma unroll
    for (int sh = 1; sh < 64; sh <<= 1) s_l += __shfl_xor(s_l, sh);
    inv = 1.f / (s_l + 1e-16f);
    for (int jj = lane; jj < deg; jj += 64) {
      float r = payf[(size_t)(beg + jj) * 8 + 6];
      atts[elist[beg + jj]] = __expf(r - M) * inv;
    }
  }

  float agg[11];
  #pragma unroll
  for (int k = 0; k < 11; k++) agg[k] = 0.f;

  int j = half;
  for (; j + 2 < deg; j += 4) {
    uint4 a0 = pay[(size_t)(beg + j) * 2],     a1 = pay[(size_t)(beg + j) * 2 + 1];
    uint4 b0 = pay[(size_t)(beg + j + 2) * 2], b1 = pay[(size_t)(beg + j + 2) * 2 + 1];
    float xa = b2f(hpb[(size_t)(int)a1.w * 32 + d]);
    float xb = b2f(hpb[(size_t)(int)b1.w * 32 + d]);
    float ca = fast ? (1.f + __shfl(einv_reg, j))
                    : (1.f + __expf(__uint_as_float(a1.z) - M) * inv);
    float cb = fast ? (1.f + __shfl(einv_reg, j + 2))
                    : (1.f + __expf(__uint_as_float(b1.z) - M) * inv);
    float cxa = ca * xa, cxb = cb * xb;
    float eva[11], evb[11];
    unpack_pay(a0, a1, eva);
    unpack_pay(b0, b1, evb);
    #pragma unroll
    for (int k = 0; k < 11; k++) agg[k] += eva[k] * cxa + evb[k] * cxb;
  }
  for (; j < deg; j += 2) {
    uint4 q0 = pay[(size_t)(beg + j) * 2], q1 = pay[(size_t)(beg + j) * 2 + 1];
    float xs = b2f(hpb[(size_t)(int)q1.w * 32 + d]);
    float c = fast ? (1.f + __shfl(einv_reg, j))
                   : (1.f + __expf(__uint_as_float(q1.z) - M) * inv);
    float cx = c * xs;
    float ev[11];
    unpack_pay(q0, q1, ev);
    #pragma unroll
    for (int k = 0; k < 11; k++) agg[k] += ev[k] * cx;
  }

  #pragma unroll
  for (int k = 0; k < 11; k++) agg[k] += __shfl_xor(agg[k], 32);

  if (half == 0) {
    bf16* arow = Abuf + (size_t)n * 352 + d * 11;
    #pragma unroll
    for (int k = 0; k < 11; k++) arow[k] = tob(agg[k]);
  }
}

// ---------------- fused conv GEMM + epilogue (+ optional next-layer h_proj) ----------------
__global__ __launch_bounds__(128) void convfused_kernel(const short* __restrict__ A, const short* __restrict__ Wt,
                                                        const short* __restrict__ owB,
                                                        const float* __restrict__ hp, float* __restrict__ h,
                                                        const float* __restrict__ convb,
                                                        const float* __restrict__ s1w, const float* __restrict__ s1b,
                                                        const float* __restrict__ s2w, const float* __restrict__ s2b,
                                                        const float* __restrict__ outb,
                                                        const float* __restrict__ initw_next,
                                                        float* __restrict__ hp_out, unsigned short* __restrict__ hpb_out,
                                                        int N) {
  __shared__ short slo[32][40];
  __shared__ float sdelta[32][36];
  __shared__ float sskipw[128];
  __shared__ float sskipb[4];
  __shared__ float scb[32];
  __shared__ float sob[32];
  __shared__ float sw1[1024];
  int tid = threadIdx.x;
  if (tid < 64) sskipw[tid] = s1w[tid];
  if (tid >= 64 && tid < 128) sskipw[tid] = s2w[tid - 64];
  if (tid < 32) sob[tid] = outb[tid];
  if (tid >= 32 && tid < 64) scb[tid - 32] = (tid - 32 < 30) ? convb[tid - 32] : 0.f;
  if (tid >= 96 && tid < 100) sskipb[tid - 96] = (tid < 98) ? s1b[tid - 96] : s2b[tid - 98];
  if (initw_next) {
    for (int i = tid; i < 1024; i += 128) sw1[i] = initw_next[i];
  }
  __syncthreads();

  int wave = tid >> 6, lane = tid & 63;
  int r16 = lane & 15, kq = lane >> 4;
  int mbase = blockIdx.x * 32 + wave * 16;

  const short* arow = A + (size_t)(mbase + r16) * 352 + kq * 8;
  const short* b0p = Wt + (size_t)r16 * 352 + kq * 8;
  const short* b1p = b0p + 16 * 352;
  f32x4v acc0 = {0.f, 0.f, 0.f, 0.f}, acc1 = {0.f, 0.f, 0.f, 0.f};
  #pragma unroll
  for (int ks = 0; ks < 11; ks++) {
    bf16x8 af = *(const bf16x8*)(arow + ks * 32);
    bf16x8 b0 = *(const bf16x8*)(b0p + ks * 32);
    bf16x8 b1 = *(const bf16x8*)(b1p + ks * 32);
    acc0 = __builtin_amdgcn_mfma_f32_16x16x32_bf16(af, b0, acc0, 0, 0, 0);
    acc1 = __builtin_amdgcn_mfma_f32_16x16x32_bf16(af, b1, acc1, 0, 0, 0);
  }
  #pragma unroll
  for (int r = 0; r < 4; r++) {
    int row = wave * 16 + kq * 4 + r;
    slo[row][r16] = (short)tobu(fmaxf(acc0[r] + scb[r16], 0.f));
    if (r16 < 14) slo[row][16 + r16] = (short)tobu(fmaxf(acc1[r] + scb[16 + r16], 0.f));
  }
  __syncthreads();

  if (tid < 64) {
    int row = tid >> 1, jx = tid & 1;
    int grow = blockIdx.x * 32 + row;
    float a1 = sskipb[jx], a2 = sskipb[2 + jx];
    if (grow < N) {
      const float* hr = hp + (size_t)grow * 32;
      #pragma unroll
      for (int dd = 0; dd < 32; dd++) {
        float hv = hr[dd];
        a1 += hv * sskipw[dd*2 + jx];
        a2 += hv * sskipw[64 + dd*2 + jx];
      }
    }
    slo[row][30 + jx] = (short)tobu(tanh_fast(a1) * tanh_fast(a2));
  }
  __syncthreads();

  bf16x8 a2f = *(const bf16x8*)&slo[wave * 16 + r16][kq * 8];
  bf16x8 bo0 = *(const bf16x8*)(owB + lane * 8);
  bf16x8 bo1 = *(const bf16x8*)(owB + 512 + lane * 8);
  f32x4v d0 = {0.f, 0.f, 0.f, 0.f}, d1 = {0.f, 0.f, 0.f, 0.f};
  d0 = __builtin_amdgcn_mfma_f32_16x16x32_bf16(a2f, bo0, d0, 0, 0, 0);
  d1 = __builtin_amdgcn_mfma_f32_16x16x32_bf16(a2f, bo1, d1, 0, 0, 0);
  #pragma unroll
  for (int r = 0; r < 4; r++) {
    int row = wave * 16 + kq * 4 + r;
    sdelta[row][r16] = d0[r] + sob[r16];
    sdelta[row][16 + r16] = d1[r] + sob[16 + r16];
  }
  __syncthreads();

  int row = tid >> 2, col0 = (tid & 3) * 8;
  int grow = blockIdx.x * 32 + row;
  if (grow < N) {
    float* hr = h + (size_t)grow * 32 + col0;
    float4 ha = *(float4*)hr;
    float4 hb = *(float4*)(hr + 4);
    float4 da = *(float4*)&sdelta[row][col0];
    float4 db = *(float4*)&sdelta[row][col0 + 4];
    ha.x += da.x; ha.y += da.y; ha.z += da.z; ha.w += da.w;
    hb.x += db.x; hb.y += db.y; hb.z += db.z; hb.w += db.w;
    *(float4*)hr = ha;
    *(float4*)(hr + 4) = hb;
    *(float4*)&sdelta[row][col0] = ha;
    *(float4*)&sdelta[row][col0 + 4] = hb;
  }
  if (initw_next) {
    __syncthreads();
    if (grow < N) {
      float o[8];
      #pragma unroll
      for (int c = 0; c < 8; c++) o[c] = 0.f;
      #pragma unroll
      for (int k = 0; k < 32; k++) {
        float hv = sdelta[row][k];
        #pragma unroll
        for (int c = 0; c < 8; c++) o[c] += hv * sw1[k*32 + col0 + c];
      }
      float* hpo = hp_out + (size_t)grow * 32 + col0;
      unsigned short* hbo = hpb_out + (size_t)grow * 32 + col0;
      #pragma unroll
      for (int c = 0; c < 8; c++) { hpo[c] = o[c]; hbo[c] = tobu(o[c]); }
    }
  }
}

// ---------------- fused pool / outh / final head ----------------
__global__ __launch_bounds__(256) void pool2_kernel(const float* __restrict__ h, const int* __restrict__ gb,
                                                    const float* __restrict__ fw, const float* __restrict__ fb,
                                                    float* __restrict__ out0, float* __restrict__ outh) {
  __shared__ float part[8][32];
  __shared__ float pooled[32];
  int g = blockIdx.x;
  int s = gb[g], e = gb[g + 1];
  int grp = threadIdx.x >> 5, d = threadIdx.x & 31;
  float acc = 0.f;
  for (int n = s + grp; n < e; n += 8) {
    float v = h[(size_t)n * 32 + d];
    outh[(size_t)n * 32 + d] = v;
    acc += v;
  }
  part[grp][d] = acc;
  __syncthreads();
  if (threadIdx.x < 32) {
    float sum = 0.f;
    #pragma unroll
    for (int i = 0; i < 8; i++) sum += part[i][d];
    pooled[d] = sum / fmaxf((float)(e - s), 1.f);
  }
  __syncthreads();
  if (threadIdx.x < 32) {
    int jx = threadIdx.x;
    float o = fb[jx];
    #pragma unroll
    for (int dd = 0; dd < 32; dd++) o += pooled[dd] * fw[dd*32 + jx];
    out0[g * 32 + jx] = o;
  }
}

extern "C" void kernel_launch(void* const* d_in, const int* in_sizes, int n_in,
                              void* d_out, int out_size, void* d_ws, size_t ws_size,
                              hipStream_t stream) {
  (void)in_sizes; (void)n_in; (void)out_size; (void)ws_size;
  const float* x      = (const float*)d_in[0];
  const float* eattr  = (const float*)d_in[1];
  const int* eidx     = (const int*)d_in[2];
  const int* batch    = (const int*)d_in[3];
  const float* emb_w  = (const float*)d_in[4];
  const float* emb_b  = (const float*)d_in[5];
  const float* init_w = (const float*)d_in[6];
  const float* e1w    = (const float*)d_in[7];
  const float* e2w    = (const float*)d_in[8];
  const float* e3w    = (const float*)d_in[9];
  const float* e4w    = (const float*)d_in[10];
  const float* convw  = (const float*)d_in[11];
  const float* convb  = (const float*)d_in[12];
  const float* attv   = (const float*)d_in[13];
  const float* s1w    = (const float*)d_in[14];
  const float* s1b    = (const float*)d_in[15];
  const float* s2w    = (const float*)d_in[16];
  const float* s2b    = (const float*)d_in[17];
  const float* outw   = (const float*)d_in[18];
  const float* outb   = (const float*)d_in[19];
  const float* finw   = (const float*)d_in[20];
  const float* finb   = (const float*)d_in[21];

  char* ws = (char*)d_ws;
  size_t off = 0;
  auto take = [&](size_t bytes) -> char* {
    char* p = ws + off;
    off += (bytes + 255) & ~(size_t)255;
    return p;
  };
  float* h    = (float*)take((size_t)N_NODES * 32 * 4);
  float* hp   = (float*)take((size_t)N_NODES * 32 * 4);
  unsigned short* hpb = (unsigned short*)take((size_t)N_NODES * 32 * 2);
  uint4* pay  = (uint4*)take((size_t)N_EDGES * 32);
  bf16*  Abuf = (bf16*)take((size_t)N_PAD * 352 * 2);
  int*   deg  = (int*)take((size_t)N_NODES * 4);
  int*   offs = (int*)take((size_t)(N_NODES + 1) * 4);
  int*   cur  = (int*)take((size_t)N_NODES * 4);
  int*   elist= (int*)take((size_t)N_EDGES * 4);
  int*   epos = (int*)take((size_t)N_EDGES * 4);
  int*   gb   = (int*)take((size_t)(N_GR + 1) * 4);
  float* wE   = (float*)take((size_t)2 * 1352 * 4);
  bf16*  Wt   = (bf16*)take((size_t)2 * 32 * 352 * 2);
  bf16*  owB  = (bf16*)take((size_t)2048 * 2);

  float* out0 = (float*)d_out;
  float* outh = out0 + N_GR * 32;
  float* outa = outh + (size_t)N_NODES * 32;

  const int* srcA = eidx;
  const int* dstA = eidx + N_EDGES;

  prep_kernel<<<107, 256, 0, stream>>>(e1w, e2w, e3w, e4w, attv, convw, outw, batch, wE, Wt, owB, gb, deg);
  hist_kernel<<<(N_EDGES + 255) / 256, 256, 0, stream>>>(dstA, deg, N_EDGES);
  scan_kernel<<<1, 1024, 0, stream>>>(deg, offs, cur, N_NODES);
  emb_hproj_kernel<<<(N_NODES + 7) / 8, 256, 0, stream>>>(x, emb_w, emb_b, init_w, h, hp, hpb, N_NODES);

  for (int l = 0; l < 2; l++) {
    edge_kernel<<<(N_EDGES + 255) / 256, 256, 0, stream>>>(
        eattr, srcA, dstA, cur, elist, epos, hpb, wE + l * 1352, pay, (l == 0) ? 1 : 0, N_EDGES);
    node_kernel<<<N_PAD / 4, 256, 0, stream>>>(offs, elist, pay, hpb,
                                               Abuf, outa + (size_t)l * N_EDGES, N_NODES);
    convfused_kernel<<<N_PAD / 32, 128, 0, stream>>>(
        (const short*)Abuf, (const short*)Wt + (size_t)l * 32 * 352, (const short*)owB + (size_t)l * 1024,
        hp, h, convb + l * 30, s1w + l * 64, s1b + l * 2, s2w + l * 64, s2b + l * 2,
        outb + l * 32,
        (l == 0) ? (init_w + 1024) : nullptr, hp, hpb, N_NODES);
  }

  pool2_kernel<<<N_GR, 256, 0, stream>>>(h, gb, finw, finb, out0, outh);
}

// Round 10
// 253.637 us; speedup vs baseline: 1.0150x; 1.0150x over previous
//
#include <hip/hip_runtime.h>
#include <hip/hip_bf16.h>

typedef __hip_bfloat16 bf16;
using f32x4v = __attribute__((ext_vector_type(4))) float;
using bf16x8 = __attribute__((ext_vector_type(8))) short;

#define N_NODES 25000
#define N_PAD   25024   // multiple of 32 for conv kernel tiles
#define N_EDGES 400000  // == 6250 * 64 exactly (no edge-kernel tail)
#define N_GR    100
#define SCAN_C  25      // 1024 * 25 = 25600 >= N_NODES

__device__ __forceinline__ bf16 tob(float v) { return __float2bfloat16(v); }
__device__ __forceinline__ unsigned short tobu(float v) {
  union { bf16 b; unsigned short u; } c; c.b = __float2bfloat16(v); return c.u;
}
__device__ __forceinline__ float b2f(unsigned short u) { return __uint_as_float(((unsigned)u) << 16); }
// clamp-free tanh: 1 - 2/(e^{2x}+1); inf-safe
__device__ __forceinline__ float tanh_fast(float x) {
  float e = __expf(2.f * x);
  return 1.f - 2.f * __builtin_amdgcn_rcpf(e + 1.f);
}

// ---------------- CSR hist + bf16 eattr pack ----------------
__global__ __launch_bounds__(256) void hist_kernel(const float* __restrict__ eattr,
                                                   const int* __restrict__ dst,
                                                   int* __restrict__ deg,
                                                   unsigned short* __restrict__ eattrB, int E) {
  __shared__ float sx[2816];
  long long base = (long long)blockIdx.x * 2816;
  for (int i = threadIdx.x; i < 2816; i += 256) {
    long long gi = base + i;
    sx[i] = (gi < (long long)E * 11) ? eattr[gi] : 0.f;
  }
  __syncthreads();
  int e = blockIdx.x * 256 + threadIdx.x;
  if (e >= E) return;
  atomicAdd(&deg[dst[e]], 1);
  const float* a = &sx[threadIdx.x * 11];
  unsigned q0 = (unsigned)tobu(a[0]) | ((unsigned)tobu(a[1]) << 16);
  unsigned q1 = (unsigned)tobu(a[2]) | ((unsigned)tobu(a[3]) << 16);
  unsigned q2 = (unsigned)tobu(a[4]) | ((unsigned)tobu(a[5]) << 16);
  unsigned q3 = (unsigned)tobu(a[6]) | ((unsigned)tobu(a[7]) << 16);
  unsigned q4 = (unsigned)tobu(a[8]) | ((unsigned)tobu(a[9]) << 16);
  unsigned q5 = (unsigned)tobu(a[10]);
  uint4* eb = (uint4*)(eattrB + (size_t)e * 16);
  eb[0] = make_uint4(q0, q1, q2, q3);
  eb[1] = make_uint4(q4, q5, 0u, 0u);
}

// one-pass scan: thread-local 25-chunk scan in registers + block scan of totals
__global__ __launch_bounds__(1024) void scan_kernel(const int* __restrict__ deg, int* __restrict__ offs,
                                                    int* __restrict__ cur, int n) {
  __shared__ int wsum[16];
  __shared__ int wpre[16];
  int t = threadIdx.x, lane = t & 63, w = t >> 6;
  int base = t * SCAN_C;
  int loc[SCAN_C];
  int s = 0;
  #pragma unroll
  for (int i = 0; i < SCAN_C; i++) {
    int idx = base + i;
    int v = (idx < n) ? deg[idx] : 0;
    loc[i] = s; s += v;
  }
  int x = s;
  #pragma unroll
  for (int sh = 1; sh < 64; sh <<= 1) { int y = __shfl_up(x, sh); if (lane >= sh) x += y; }
  if (lane == 63) wsum[w] = x;
  __syncthreads();
  if (w == 0 && lane < 16) {
    int ws_ = wsum[lane], xs = ws_;
    #pragma unroll
    for (int sh = 1; sh < 16; sh <<= 1) { int y = __shfl_up(xs, sh); if (lane >= sh) xs += y; }
    wpre[lane] = xs - ws_;
  }
  __syncthreads();
  int excl = wpre[w] + x - s;
  #pragma unroll
  for (int i = 0; i < SCAN_C; i++) {
    int idx = base + i;
    if (idx < n) { int o = excl + loc[i]; offs[idx] = o; cur[idx] = o; }
  }
  if (t == 1023) offs[n] = excl + s;
}

// ---------------- weight prep (+ zero deg + graph bounds) ----------------
// W1B per layer: [5 tiles][16 n][32 k] bf16, col np = t*16+n of [e1|e2|e3] (k<11 real)
// W2B per layer: [16 n][48 k] bf16, = e4[k][n] (k<44, n<11 real)
// Wt  per layer (32x352 bf16): Wt[o][d*11+kk] = conv_w[kk][d][o]  (o>=30 zero)
// owB per layer (2x64x8 bf16)
__global__ __launch_bounds__(256) void prep_kernel(const float* __restrict__ e1, const float* __restrict__ e2,
                                                   const float* __restrict__ e3, const float* __restrict__ e4,
                                                   const float* __restrict__ convw, const float* __restrict__ outw,
                                                   const int* __restrict__ batch,
                                                   unsigned short* __restrict__ W1B,
                                                   unsigned short* __restrict__ W2B,
                                                   bf16* __restrict__ Wt, bf16* __restrict__ owB,
                                                   int* __restrict__ gb, int* __restrict__ deg) {
  int i = blockIdx.x * blockDim.x + threadIdx.x;
  if (i < N_NODES) deg[i] = 0;
  if (i < 5120) {
    int l = i / 2560, r = i % 2560;
    int t = r >> 9, rem = r & 511, n16 = rem >> 5, k = rem & 31;
    int np = t * 16 + n16;
    float v = 0.f;
    if (k < 11 && np < 66) {
      if (np < 22)      v = e1[l*242 + k*22 + np];
      else if (np < 44) v = e2[l*242 + k*22 + (np - 22)];
      else              v = e3[l*242 + k*22 + (np - 44)];
    }
    W1B[i] = tobu(v);
  }
  int j2 = i - 5120;
  if (j2 >= 0 && j2 < 1536) {
    int l = j2 / 768, r = j2 % 768, n = r / 48, k = r % 48;
    float v = (n < 11 && k < 44) ? e4[l*484 + k*11 + n] : 0.f;
    W2B[j2] = tobu(v);
  }
  int t_ = i - 6656;
  if (t_ >= 0 && t_ < 22528) {
    int l = t_ / 11264, q = t_ % 11264;
    int o = q / 352, dk = q % 352;
    int d = dk / 11, kk = dk % 11;
    float v = 0.f;
    if (o < 30) v = convw[l*10560 + (kk*32 + d)*30 + o];
    Wt[t_] = tob(v);
  }
  int u = i - 29184;
  if (u >= 0 && u < 2048) {
    int l = u >> 10, rem = u & 1023;
    int hf = rem >> 9, rem2 = rem & 511;
    int lane = rem2 >> 3, j = rem2 & 7;
    int k = (lane >> 4) * 8 + j, n = lane & 15;
    owB[u] = tob(outw[l*1024 + k*32 + hf*16 + n]);
  }
  int g = i - 31232;
  if (g >= 0 && g <= N_GR) {
    if (g == N_GR) { gb[g] = N_NODES; }
    else {
      int lo = 0, hi = N_NODES;
      while (lo < hi) { int mid = (lo + hi) >> 1; if (batch[mid] < g) lo = mid + 1; else hi = mid; }
      gb[g] = lo;
    }
  }
}

// ---------------- fused embedding + h_proj(layer 0) ----------------
__global__ __launch_bounds__(256) void emb_hproj_kernel(const float* __restrict__ x, const float* __restrict__ w,
                                                        const float* __restrict__ b, const float* __restrict__ w1,
                                                        float* __restrict__ h, float* __restrict__ hp,
                                                        unsigned short* __restrict__ hpb, int N) {
  __shared__ float semb[16 * 32];
  __shared__ float sw1[32 * 32];
  __shared__ float sb[32];
  __shared__ float sx[8][16];
  __shared__ float sh[8][33];
  int tid = threadIdx.x;
  for (int i = tid; i < 16 * 32; i += 256) semb[i] = w[i];
  for (int i = tid; i < 32 * 32; i += 256) sw1[i] = w1[i];
  if (tid < 32) sb[tid] = b[tid];
  int nb = blockIdx.x * 8;
  if (tid < 128) {
    int n = nb + (tid >> 4), k = tid & 15;
    sx[tid >> 4][k] = (n < N) ? x[(size_t)n * 16 + k] : 0.f;
  }
  __syncthreads();
  int grp = tid >> 5, d = tid & 31;
  int n = nb + grp;
  float acc = sb[d];
  #pragma unroll
  for (int k = 0; k < 16; k++) acc += sx[grp][k] * semb[k*32 + d];
  sh[grp][d] = acc;
  if (n < N) h[(size_t)n * 32 + d] = acc;
  __syncthreads();
  float hpv = 0.f;
  #pragma unroll
  for (int k = 0; k < 32; k++) hpv += sh[grp][k] * sw1[k*32 + d];
  if (n < N) {
    hp[(size_t)n * 32 + d] = hpv;
    hpb[(size_t)n * 32 + d] = tobu(hpv);
  }
}

// ---------------- edge MLP via MFMA: 4 waves x 16-edge tiles ----------------
__global__ __launch_bounds__(256) void edge_mfma_kernel(const unsigned short* __restrict__ eattrB,
                                                        const unsigned short* __restrict__ W1Bl,
                                                        const unsigned short* __restrict__ W2Bl,
                                                        const float* __restrict__ attvl,
                                                        const int* __restrict__ srcA,
                                                        const int* __restrict__ dstA,
                                                        int* __restrict__ cur,
                                                        int* __restrict__ elist,
                                                        int* __restrict__ epos,
                                                        const unsigned short* __restrict__ hpb,
                                                        uint4* __restrict__ pay, int first) {
  __shared__ __align__(16) unsigned short sW1[5][16][40]; // padded rows (80B) for banking+align
  __shared__ __align__(16) unsigned short sW2[16][56];
  __shared__ float sattv[32];
  __shared__ float raw1[4][16][68];
  __shared__ __align__(16) unsigned short sv[4][16][56];
  __shared__ float sea[4][16][12];
  int tid = threadIdx.x;
  for (int i = tid; i < 2560; i += 256) {
    int t = i >> 9, rem = i & 511;
    sW1[t][rem >> 5][rem & 31] = W1Bl[i];
  }
  for (int i = tid; i < 768; i += 256) sW2[i / 48][i % 48] = W2Bl[i];
  if (tid < 128) sW2[tid >> 3][48 + (tid & 7)] = 0;
  if (tid < 32) sattv[tid] = attvl[tid];
  __syncthreads();

  int w = tid >> 6, lane = tid & 63;
  int r16 = lane & 15, kq = lane >> 4;
  int ebase = blockIdx.x * 64 + w * 16;

  bf16x8 zz = {0, 0, 0, 0, 0, 0, 0, 0};
  // ---- GEMM1: raw[e][np] = eattr[e][:] . W66[:][np] ----
  bf16x8 a1 = (kq < 2) ? *(const bf16x8*)(eattrB + (size_t)(ebase + r16) * 16 + kq * 8) : zz;
  f32x4v c[5];
  #pragma unroll
  for (int t = 0; t < 5; t++) {
    bf16x8 b = *(const bf16x8*)&sW1[t][r16][kq * 8];
    f32x4v z4 = {0.f, 0.f, 0.f, 0.f};
    c[t] = __builtin_amdgcn_mfma_f32_16x16x32_bf16(a1, b, z4, 0, 0, 0);
  }
  #pragma unroll
  for (int t = 0; t < 5; t++) {
    #pragma unroll
    for (int r = 0; r < 4; r++) {
      int col = t * 16 + r16;
      if (col < 66) raw1[w][kq * 4 + r][col] = c[t][r];
    }
  }
  // ---- nonlinearity (wave-synchronous LDS reuse) ----
  {
    int e = lane & 15, q = lane >> 4;
    #pragma unroll
    for (int m = 0; m < 11; m++) {
      int i = q * 11 + m;
      float v;
      if (i < 22) v = fmaxf(raw1[w][e][i], 0.f);
      else        v = tanh_fast(raw1[w][e][i]) * tanh_fast(raw1[w][e][i + 22]);
      sv[w][e][i] = tobu(v);
    }
    if (q == 3) { sv[w][e][44] = 0; sv[w][e][45] = 0; sv[w][e][46] = 0; sv[w][e][47] = 0; }
  }
  // ---- GEMM2: ea[e][n] = v[e][:44] . e4[:44][n], K=48 in 2 MFMA ----
  bf16x8 a2lo = *(const bf16x8*)&sv[w][r16][kq * 8];
  bf16x8 a2hi = (kq < 2) ? *(const bf16x8*)&sv[w][r16][32 + kq * 8] : zz;
  bf16x8 b2lo = *(const bf16x8*)&sW2[r16][kq * 8];
  bf16x8 b2hi = (kq < 2) ? *(const bf16x8*)&sW2[r16][32 + kq * 8] : zz;
  f32x4v z4 = {0.f, 0.f, 0.f, 0.f};
  f32x4v c2 = __builtin_amdgcn_mfma_f32_16x16x32_bf16(a2lo, b2lo, z4, 0, 0, 0);
  c2 = __builtin_amdgcn_mfma_f32_16x16x32_bf16(a2hi, b2hi, c2, 0, 0, 0);
  if (r16 < 11) {
    #pragma unroll
    for (int r = 0; r < 4; r++) sea[w][kq * 4 + r][r16] = fmaxf(c2[r], 0.f);
  }
  // ---- finisher: 4 lanes per edge ----
  {
    int e = lane >> 2, part = lane & 3;
    int eid = ebase + e;
    int pp = 0;
    if (first) {
      if (part == 0) { pp = atomicAdd(&cur[dstA[eid]], 1); elist[pp] = eid; epos[eid] = pp; }
      pp = __shfl(pp, lane & ~3);
    } else {
      pp = epos[eid];
    }
    float msum = 0.f;
    #pragma unroll
    for (int m = 0; m < 3; m++) { int idx = part * 3 + m; if (idx < 11) msum += sea[w][e][idx]; }
    msum += __shfl_xor(msum, 1);
    msum += __shfl_xor(msum, 2);
    float mean = msum * (1.f / 11.f);
    int s = srcA[eid];
    const uint2* hb = (const uint2*)(hpb + (size_t)s * 32 + part * 8);
    uint2 h0 = hb[0], h1 = hb[1];
    const float* av = sattv + part * 8;
    float dot = b2f((unsigned short)h0.x) * av[0] + b2f((unsigned short)(h0.x >> 16)) * av[1]
              + b2f((unsigned short)h0.y) * av[2] + b2f((unsigned short)(h0.y >> 16)) * av[3]
              + b2f((unsigned short)h1.x) * av[4] + b2f((unsigned short)(h1.x >> 16)) * av[5]
              + b2f((unsigned short)h1.y) * av[6] + b2f((unsigned short)(h1.y >> 16)) * av[7];
    dot += __shfl_xor(dot, 1);
    dot += __shfl_xor(dot, 2);
    float raw = mean * dot;
    if (part == 0) {
      unsigned q0 = (unsigned)tobu(sea[w][e][0]) | ((unsigned)tobu(sea[w][e][1]) << 16);
      unsigned q1 = (unsigned)tobu(sea[w][e][2]) | ((unsigned)tobu(sea[w][e][3]) << 16);
      unsigned q2 = (unsigned)tobu(sea[w][e][4]) | ((unsigned)tobu(sea[w][e][5]) << 16);
      unsigned q3 = (unsigned)tobu(sea[w][e][6]) | ((unsigned)tobu(sea[w][e][7]) << 16);
      pay[(size_t)pp * 2] = make_uint4(q0, q1, q2, q3);
    } else if (part == 1) {
      unsigned q4 = (unsigned)tobu(sea[w][e][8]) | ((unsigned)tobu(sea[w][e][9]) << 16);
      unsigned q5 = (unsigned)tobu(sea[w][e][10]);
      pay[(size_t)pp * 2 + 1] = make_uint4(q4, q5, __float_as_uint(raw), (unsigned)s);
    }
  }
}

// ---------------- per-node aggregation: softmax scan then branch-free reduction ----------------
__device__ __forceinline__ void unpack_pay(uint4 p0, uint4 p1, float* ev) {
  ev[0] = b2f((unsigned short)p0.x); ev[1] = b2f((unsigned short)(p0.x >> 16));
  ev[2] = b2f((unsigned short)p0.y); ev[3] = b2f((unsigned short)(p0.y >> 16));
  ev[4] = b2f((unsigned short)p0.z); ev[5] = b2f((unsigned short)(p0.z >> 16));
  ev[6] = b2f((unsigned short)p0.w); ev[7] = b2f((unsigned short)(p0.w >> 16));
  ev[8] = b2f((unsigned short)p1.x); ev[9] = b2f((unsigned short)(p1.x >> 16));
  ev[10] = b2f((unsigned short)p1.y);
}

__global__ __launch_bounds__(256) void node_kernel(const int* __restrict__ offs, const int* __restrict__ elist,
                                                   const uint4* __restrict__ pay,
                                                   const unsigned short* __restrict__ hpb,
                                                   bf16* __restrict__ Abuf, float* __restrict__ atts, int N) {
  int wid = threadIdx.x >> 6, lane = threadIdx.x & 63;
  int half = lane >> 5, d = lane & 31;
  int n = blockIdx.x * 4 + wid;
  if (n >= N_PAD) return;
  int beg = 0, deg = 0;
  if (n < N) { beg = offs[n]; deg = offs[n + 1] - beg; }
  const float* payf = (const float*)pay;

  float M, inv;
  float einv_reg = 0.f;
  bool fast = (deg <= 64);
  if (fast) {
    float r = (lane < deg) ? payf[(size_t)(beg + lane) * 8 + 6] : -1e30f;
    float mm = r;
    #pragma unroll
    for (int sh = 1; sh < 64; sh <<= 1) mm = fmaxf(mm, __shfl_xor(mm, sh));
    M = mm;
    float ex = (lane < deg) ? __expf(r - M) : 0.f;
    float ss = ex;
    #pragma unroll
    for (int sh = 1; sh < 64; sh <<= 1) ss += __shfl_xor(ss, sh);
    inv = 1.f / (ss + 1e-16f);
    einv_reg = ex * inv;
    if (lane < deg) atts[elist[beg + lane]] = einv_reg;
  } else {
    float m_l = -1e30f;
    for (int jj = lane; jj < deg; jj += 64)
      m_l = fmaxf(m_l, payf[(size_t)(beg + jj) * 8 + 6]);
    #pragma unroll
    for (int sh = 1; sh < 64; sh <<= 1) m_l = fmaxf(m_l, __shfl_xor(m_l, sh));
    M = m_l;
    float s_l = 0.f;
    for (int jj = lane; jj < deg; jj += 64)
      s_l += __expf(payf[(size_t)(beg + jj) * 8 + 6] - M);
    #pragma unroll
    for (int sh = 1; sh < 64; sh <<= 1) s_l += __shfl_xor(s_l, sh);
    inv = 1.f / (s_l + 1e-16f);
    for (int jj = lane; jj < deg; jj += 64) {
      float r = payf[(size_t)(beg + jj) * 8 + 6];
      atts[elist[beg + jj]] = __expf(r - M) * inv;
    }
  }

  float agg[11];
  #pragma unroll
  for (int k = 0; k < 11; k++) agg[k] = 0.f;

  int j = half;
  for (; j + 2 < deg; j += 4) {
    uint4 a0 = pay[(size_t)(beg + j) * 2],     a1 = pay[(size_t)(beg + j) * 2 + 1];
    uint4 b0 = pay[(size_t)(beg + j + 2) * 2], b1 = pay[(size_t)(beg + j + 2) * 2 + 1];
    float xa = b2f(hpb[(size_t)(int)a1.w * 32 + d]);
    float xb = b2f(hpb[(size_t)(int)b1.w * 32 + d]);
    float ca = fast ? (1.f + __shfl(einv_reg, j))
                    : (1.f + __expf(__uint_as_float(a1.z) - M) * inv);
    float cb = fast ? (1.f + __shfl(einv_reg, j + 2))
                    : (1.f + __expf(__uint_as_float(b1.z) - M) * inv);
    float cxa = ca * xa, cxb = cb * xb;
    float eva[11], evb[11];
    unpack_pay(a0, a1, eva);
    unpack_pay(b0, b1, evb);
    #pragma unroll
    for (int k = 0; k < 11; k++) agg[k] += eva[k] * cxa + evb[k] * cxb;
  }
  for (; j < deg; j += 2) {
    uint4 q0 = pay[(size_t)(beg + j) * 2], q1 = pay[(size_t)(beg + j) * 2 + 1];
    float xs = b2f(hpb[(size_t)(int)q1.w * 32 + d]);
    float c = fast ? (1.f + __shfl(einv_reg, j))
                   : (1.f + __expf(__uint_as_float(q1.z) - M) * inv);
    float cx = c * xs;
    float ev[11];
    unpack_pay(q0, q1, ev);
    #pragma unroll
    for (int k = 0; k < 11; k++) agg[k] += ev[k] * cx;
  }

  #pragma unroll
  for (int k = 0; k < 11; k++) agg[k] += __shfl_xor(agg[k], 32);

  if (half == 0) {
    bf16* arow = Abuf + (size_t)n * 352 + d * 11;
    #pragma unroll
    for (int k = 0; k < 11; k++) arow[k] = tob(agg[k]);
  }
}

// ---------------- fused conv GEMM + epilogue (+ optional next-layer h_proj) ----------------
__global__ __launch_bounds__(128) void convfused_kernel(const short* __restrict__ A, const short* __restrict__ Wt,
                                                        const short* __restrict__ owB,
                                                        const float* __restrict__ hp, float* __restrict__ h,
                                                        const float* __restrict__ convb,
                                                        const float* __restrict__ s1w, const float* __restrict__ s1b,
                                                        const float* __restrict__ s2w, const float* __restrict__ s2b,
                                                        const float* __restrict__ outb,
                                                        const float* __restrict__ initw_next,
                                                        float* __restrict__ hp_out, unsigned short* __restrict__ hpb_out,
                                                        int N) {
  __shared__ short slo[32][40];
  __shared__ float sdelta[32][36];
  __shared__ float sskipw[128];
  __shared__ float sskipb[4];
  __shared__ float scb[32];
  __shared__ float sob[32];
  __shared__ float sw1[1024];
  int tid = threadIdx.x;
  if (tid < 64) sskipw[tid] = s1w[tid];
  if (tid >= 64 && tid < 128) sskipw[tid] = s2w[tid - 64];
  if (tid < 32) sob[tid] = outb[tid];
  if (tid >= 32 && tid < 64) scb[tid - 32] = (tid - 32 < 30) ? convb[tid - 32] : 0.f;
  if (tid >= 96 && tid < 100) sskipb[tid - 96] = (tid < 98) ? s1b[tid - 96] : s2b[tid - 98];
  if (initw_next) {
    for (int i = tid; i < 1024; i += 128) sw1[i] = initw_next[i];
  }
  __syncthreads();

  int wave = tid >> 6, lane = tid & 63;
  int r16 = lane & 15, kq = lane >> 4;
  int mbase = blockIdx.x * 32 + wave * 16;

  const short* arow = A + (size_t)(mbase + r16) * 352 + kq * 8;
  const short* b0p = Wt + (size_t)r16 * 352 + kq * 8;
  const short* b1p = b0p + 16 * 352;
  f32x4v acc0 = {0.f, 0.f, 0.f, 0.f}, acc1 = {0.f, 0.f, 0.f, 0.f};
  #pragma unroll
  for (int ks = 0; ks < 11; ks++) {
    bf16x8 af = *(const bf16x8*)(arow + ks * 32);
    bf16x8 b0 = *(const bf16x8*)(b0p + ks * 32);
    bf16x8 b1 = *(const bf16x8*)(b1p + ks * 32);
    acc0 = __builtin_amdgcn_mfma_f32_16x16x32_bf16(af, b0, acc0, 0, 0, 0);
    acc1 = __builtin_amdgcn_mfma_f32_16x16x32_bf16(af, b1, acc1, 0, 0, 0);
  }
  #pragma unroll
  for (int r = 0; r < 4; r++) {
    int row = wave * 16 + kq * 4 + r;
    slo[row][r16] = (short)tobu(fmaxf(acc0[r] + scb[r16], 0.f));
    if (r16 < 14) slo[row][16 + r16] = (short)tobu(fmaxf(acc1[r] + scb[16 + r16], 0.f));
  }
  __syncthreads();

  if (tid < 64) {
    int row = tid >> 1, jx = tid & 1;
    int grow = blockIdx.x * 32 + row;
    float a1 = sskipb[jx], a2 = sskipb[2 + jx];
    if (grow < N) {
      const float* hr = hp + (size_t)grow * 32;
      #pragma unroll
      for (int dd = 0; dd < 32; dd++) {
        float hv = hr[dd];
        a1 += hv * sskipw[dd*2 + jx];
        a2 += hv * sskipw[64 + dd*2 + jx];
      }
    }
    slo[row][30 + jx] = (short)tobu(tanh_fast(a1) * tanh_fast(a2));
  }
  __syncthreads();

  bf16x8 a2f = *(const bf16x8*)&slo[wave * 16 + r16][kq * 8];
  bf16x8 bo0 = *(const bf16x8*)(owB + lane * 8);
  bf16x8 bo1 = *(const bf16x8*)(owB + 512 + lane * 8);
  f32x4v d0 = {0.f, 0.f, 0.f, 0.f}, d1 = {0.f, 0.f, 0.f, 0.f};
  d0 = __builtin_amdgcn_mfma_f32_16x16x32_bf16(a2f, bo0, d0, 0, 0, 0);
  d1 = __builtin_amdgcn_mfma_f32_16x16x32_bf16(a2f, bo1, d1, 0, 0, 0);
  #pragma unroll
  for (int r = 0; r < 4; r++) {
    int row = wave * 16 + kq * 4 + r;
    sdelta[row][r16] = d0[r] + sob[r16];
    sdelta[row][16 + r16] = d1[r] + sob[16 + r16];
  }
  __syncthreads();

  int row = tid >> 2, col0 = (tid & 3) * 8;
  int grow = blockIdx.x * 32 + row;
  if (grow < N) {
    float* hr = h + (size_t)grow * 32 + col0;
    float4 ha = *(float4*)hr;
    float4 hb = *(float4*)(hr + 4);
    float4 da = *(float4*)&sdelta[row][col0];
    float4 db = *(float4*)&sdelta[row][col0 + 4];
    ha.x += da.x; ha.y += da.y; ha.z += da.z; ha.w += da.w;
    hb.x += db.x; hb.y += db.y; hb.z += db.z; hb.w += db.w;
    *(float4*)hr = ha;
    *(float4*)(hr + 4) = hb;
    *(float4*)&sdelta[row][col0] = ha;
    *(float4*)&sdelta[row][col0 + 4] = hb;
  }
  if (initw_next) {
    __syncthreads();
    if (grow < N) {
      float o[8];
      #pragma unroll
      for (int c = 0; c < 8; c++) o[c] = 0.f;
      #pragma unroll
      for (int k = 0; k < 32; k++) {
        float hv = sdelta[row][k];
        #pragma unroll
        for (int c = 0; c < 8; c++) o[c] += hv * sw1[k*32 + col0 + c];
      }
      float* hpo = hp_out + (size_t)grow * 32 + col0;
      unsigned short* hbo = hpb_out + (size_t)grow * 32 + col0;
      #pragma unroll
      for (int c = 0; c < 8; c++) { hpo[c] = o[c]; hbo[c] = tobu(o[c]); }
    }
  }
}

// ---------------- fused pool / outh / final head ----------------
__global__ __launch_bounds__(256) void pool2_kernel(const float* __restrict__ h, const int* __restrict__ gb,
                                                    const float* __restrict__ fw, const float* __restrict__ fb,
                                                    float* __restrict__ out0, float* __restrict__ outh) {
  __shared__ float part[8][32];
  __shared__ float pooled[32];
  int g = blockIdx.x;
  int s = gb[g], e = gb[g + 1];
  int grp = threadIdx.x >> 5, d = threadIdx.x & 31;
  float acc = 0.f;
  for (int n = s + grp; n < e; n += 8) {
    float v = h[(size_t)n * 32 + d];
    outh[(size_t)n * 32 + d] = v;
    acc += v;
  }
  part[grp][d] = acc;
  __syncthreads();
  if (threadIdx.x < 32) {
    float sum = 0.f;
    #pragma unroll
    for (int i = 0; i < 8; i++) sum += part[i][d];
    pooled[d] = sum / fmaxf((float)(e - s), 1.f);
  }
  __syncthreads();
  if (threadIdx.x < 32) {
    int jx = threadIdx.x;
    float o = fb[jx];
    #pragma unroll
    for (int dd = 0; dd < 32; dd++) o += pooled[dd] * fw[dd*32 + jx];
    out0[g * 32 + jx] = o;
  }
}

extern "C" void kernel_launch(void* const* d_in, const int* in_sizes, int n_in,
                              void* d_out, int out_size, void* d_ws, size_t ws_size,
                              hipStream_t stream) {
  (void)in_sizes; (void)n_in; (void)out_size; (void)ws_size;
  const float* x      = (const float*)d_in[0];
  const float* eattr  = (const float*)d_in[1];
  const int* eidx     = (const int*)d_in[2];
  const int* batch    = (const int*)d_in[3];
  const float* emb_w  = (const float*)d_in[4];
  const float* emb_b  = (const float*)d_in[5];
  const float* init_w = (const float*)d_in[6];
  const float* e1w    = (const float*)d_in[7];
  const float* e2w    = (const float*)d_in[8];
  const float* e3w    = (const float*)d_in[9];
  const float* e4w    = (const float*)d_in[10];
  const float* convw  = (const float*)d_in[11];
  const float* convb  = (const float*)d_in[12];
  const float* attv   = (const float*)d_in[13];
  const float* s1w    = (const float*)d_in[14];
  const float* s1b    = (const float*)d_in[15];
  const float* s2w    = (const float*)d_in[16];
  const float* s2b    = (const float*)d_in[17];
  const float* outw   = (const float*)d_in[18];
  const float* outb   = (const float*)d_in[19];
  const float* finw   = (const float*)d_in[20];
  const float* finb   = (const float*)d_in[21];

  char* ws = (char*)d_ws;
  size_t off = 0;
  auto take = [&](size_t bytes) -> char* {
    char* p = ws + off;
    off += (bytes + 255) & ~(size_t)255;
    return p;
  };
  float* h    = (float*)take((size_t)N_NODES * 32 * 4);
  float* hp   = (float*)take((size_t)N_NODES * 32 * 4);
  unsigned short* hpb = (unsigned short*)take((size_t)N_NODES * 32 * 2);
  uint4* pay  = (uint4*)take((size_t)N_EDGES * 32);
  unsigned short* eattrB = (unsigned short*)take((size_t)N_EDGES * 16 * 2);
  bf16*  Abuf = (bf16*)take((size_t)N_PAD * 352 * 2);
  int*   deg  = (int*)take((size_t)N_NODES * 4);
  int*   offs = (int*)take((size_t)(N_NODES + 1) * 4);
  int*   cur  = (int*)take((size_t)N_NODES * 4);
  int*   elist= (int*)take((size_t)N_EDGES * 4);
  int*   epos = (int*)take((size_t)N_EDGES * 4);
  int*   gb   = (int*)take((size_t)(N_GR + 1) * 4);
  unsigned short* W1B = (unsigned short*)take((size_t)2 * 2560 * 2);
  unsigned short* W2B = (unsigned short*)take((size_t)2 * 768 * 2);
  bf16*  Wt   = (bf16*)take((size_t)2 * 32 * 352 * 2);
  bf16*  owB  = (bf16*)take((size_t)2048 * 2);

  float* out0 = (float*)d_out;
  float* outh = out0 + N_GR * 32;
  float* outa = outh + (size_t)N_NODES * 32;

  const int* srcA = eidx;
  const int* dstA = eidx + N_EDGES;

  prep_kernel<<<123, 256, 0, stream>>>(e1w, e2w, e3w, e4w, convw, outw, batch,
                                       W1B, W2B, Wt, owB, gb, deg);
  hist_kernel<<<(N_EDGES + 255) / 256, 256, 0, stream>>>(eattr, dstA, deg, eattrB, N_EDGES);
  scan_kernel<<<1, 1024, 0, stream>>>(deg, offs, cur, N_NODES);
  emb_hproj_kernel<<<(N_NODES + 7) / 8, 256, 0, stream>>>(x, emb_w, emb_b, init_w, h, hp, hpb, N_NODES);

  for (int l = 0; l < 2; l++) {
    edge_mfma_kernel<<<N_EDGES / 64, 256, 0, stream>>>(
        eattrB, W1B + (size_t)l * 2560, W2B + (size_t)l * 768, attv + l * 32,
        srcA, dstA, cur, elist, epos, hpb, pay, (l == 0) ? 1 : 0);
    node_kernel<<<N_PAD / 4, 256, 0, stream>>>(offs, elist, pay, hpb,
                                               Abuf, outa + (size_t)l * N_EDGES, N_NODES);
    convfused_kernel<<<N_PAD / 32, 128, 0, stream>>>(
        (const short*)Abuf, (const short*)Wt + (size_t)l * 32 * 352, (const short*)owB + (size_t)l * 1024,
        hp, h, convb + l * 30, s1w + l * 64, s1b + l * 2, s2w + l * 64, s2b + l * 2,
        outb + l * 32,
        (l == 0) ? (init_w + 1024) : nullptr, hp, hpb, N_NODES);
  }

  pool2_kernel<<<N_GR, 256, 0, stream>>>(h, gb, finw, finb, out0, outh);
}